// Round 16
// baseline (63.978 us; speedup 1.0000x reference)
//
#include <hip/hip_runtime.h>

// Attention_55336358642806: x@W_qkv+b -> 4-head causal attention -> @W_out+b
// B=16 S=1024 E=256 H=4 D=64.  All-MFMA bf16 pipeline, fp32 accumulation.
//
// r15: XCD-AFFINITY CHAINING (single variable vs r14).  g1/g2's decode already
// gives XCD x the batches {2x,2x+1}; this round aligns the other two hops:
//   conv_all x-part: block x+8j writes rows [x*2048+j*8) -> xb local to g1.
//   attn: XCD x processes b in {2x,2x+1} (all heads) -> K/V/Q first-touch
//         reads hit the LOCAL L2 that g1's XCD x wrote; O-writes land where
//         g2's XCD x reads.
// Model being tested: attn@REP1 ~40us is cross-XCD first-touch latency
// (r10's REP=4 ran 4x work in 1.77x time -> warm-gen 10us vs cold 40us).
//
// ws layout (bytes):
//   [0,        393216)   W_qkvT bf16 [768][256]
//   [393216,   524288)   W_outT bf16 [256][256]
//   [524288, 17301504)   qk     bf16 [16384][512]  (Q cols 0..255, K 256..511;
//                                                   attn out overwrites Q cols)
//   [17301504,25690112)  Vt     bf16 [64 bh][16 kvt][64 d][64 kv]
//   [25690112,34078720)  xb     bf16 [16384][256]

typedef unsigned short ushort_t;
typedef __bf16 bf16x8 __attribute__((ext_vector_type(8)));
typedef __bf16 bf16x4 __attribute__((ext_vector_type(4)));
typedef unsigned short u16x8 __attribute__((ext_vector_type(8)));
typedef unsigned short u16x4 __attribute__((ext_vector_type(4)));
typedef float f32x4 __attribute__((ext_vector_type(4)));
typedef short s16x4 __attribute__((ext_vector_type(4)));

__device__ __forceinline__ ushort_t f2bf(float f) {
  __bf16 h = (__bf16)f;
  return __builtin_bit_cast(ushort_t, h);
}

__device__ __forceinline__ void gload_lds16(const ushort_t* g, ushort_t* l) {
  __builtin_amdgcn_global_load_lds(
      (const __attribute__((address_space(1))) unsigned int*)g,
      (__attribute__((address_space(3))) unsigned int*)l, 16, 0, 0);
}

#define BARRIER_RAW() do { __builtin_amdgcn_s_barrier(); \
                           __builtin_amdgcn_sched_barrier(0); } while (0)

__device__ __forceinline__ f32x4 mfma16(bf16x4 a, bf16x4 b, f32x4 c) {
#if __has_builtin(__builtin_amdgcn_mfma_f32_16x16x16bf16_1k)
  return __builtin_amdgcn_mfma_f32_16x16x16bf16_1k(
      __builtin_bit_cast(s16x4, a), __builtin_bit_cast(s16x4, b), c, 0, 0, 0);
#elif __has_builtin(__builtin_amdgcn_mfma_f32_16x16x16_bf16)
  return __builtin_amdgcn_mfma_f32_16x16x16_bf16(a, b, c, 0, 0, 0);
#else
  f32x4 d = c;
  asm volatile("v_mfma_f32_16x16x16_bf16 %0, %1, %2, %0"
               : "+v"(d) : "v"(a), "v"(b));
  return d;
#endif
}

// ------------- kernel 0: convert x->bf16 + transpose weights ----------------
// x-part XCD-affine: block x+8j (x = XCD under blockIdx%8 round-robin) writes
// xb rows [x*2048 + j*8, +8) so g1's XCD x finds its A rows in the local L2.
__global__ __launch_bounds__(256)
void convert_all(const float* __restrict__ x,
                 const float* __restrict__ Wq, const float* __restrict__ Wo,
                 ushort_t* __restrict__ xb,
                 ushort_t* __restrict__ WqT, ushort_t* __restrict__ WoT)
{
  int blk = blockIdx.x;
  if (blk < 2048) {                 // x: 8 floats/thread, coalesced, XCD-affine
    const int xc = blk & 7, j = blk >> 3;
    const size_t base = (size_t)xc * 524288 + (size_t)j * 2048 + threadIdx.x * 8;
    float4 v0 = *(const float4*)&x[base];
    float4 v1 = *(const float4*)&x[base + 4];
    u16x8 ov;
    ov[0]=f2bf(v0.x); ov[1]=f2bf(v0.y); ov[2]=f2bf(v0.z); ov[3]=f2bf(v0.w);
    ov[4]=f2bf(v1.x); ov[5]=f2bf(v1.y); ov[6]=f2bf(v1.z); ov[7]=f2bf(v1.w);
    *(u16x8*)&xb[base] = ov;
    return;
  }
  blk -= 2048;                      // weights: LDS-tile transpose, coalesced
  __shared__ float t[64][65];
  const float* src; ushort_t* dst; int ld_src, k0, n0;
  if (blk < 48) { src = Wq; dst = WqT; ld_src = 768;
                  k0 = (blk / 12) * 64; n0 = (blk % 12) * 64; }
  else { blk -= 48; src = Wo; dst = WoT; ld_src = 256;
         k0 = (blk / 4) * 64; n0 = (blk % 4) * 64; }
  const int tr = threadIdx.x >> 6, tc = threadIdx.x & 63;
  #pragma unroll
  for (int i = 0; i < 16; ++i) {
    const int r = i * 4 + tr;
    t[r][tc] = src[(size_t)(k0 + r) * ld_src + n0 + tc];
  }
  __syncthreads();
  #pragma unroll
  for (int i = 0; i < 16; ++i) {
    const int r = i * 4 + tr;
    dst[(size_t)(n0 + r) * 256 + k0 + tc] = f2bf(t[tc][r]);
  }
}

// ---------------- GEMM v4 (r9/r14 measured-best, unchanged) -----------------
// XCD x owns gidx [x*chunk,(x+1)*chunk) -> m-rows [x*2048,(x+1)*2048) =
// batches {2x,2x+1} (already produce-side aligned).
template<int OUT_MODE, int NB>            // OUT_MODE: 0=qkv split, 1=f32
__global__ __launch_bounds__(256, 2)
void gemm_bias(const ushort_t* __restrict__ A, int ldA,
               const ushort_t* __restrict__ Bt,
               const float* __restrict__ bias,
               void* __restrict__ Outp, int ldOut,
               ushort_t* __restrict__ Vt)
{
  __shared__ ushort_t Bl[64][256];          // 32 KB; 16B-chunk c at c^(r&7)
  __shared__ ushort_t Al[4][3][64][32];     // 48 KB; chunk c at c^((r>>1)&3)

  const int tid = threadIdx.x;
  const int lane = tid & 63;
  const int w  = tid >> 6;
  const int l15 = lane & 15, g = lane >> 4;

  const int nwg = NB * 64;
  const int inner = (int)blockIdx.x % nwg;
  const int chunkXCD = nwg >> 3;
  const int gidx = (inner & 7) * chunkXCD + (inner >> 3);
  const int n0 = (gidx % NB) * 64;
  const int mBase = (gidx / NB) * 256;
  const int mw = mBase + w * 64;            // this wave's 64 rows
  const bool vmode = (OUT_MODE == 0) && (n0 >= 512);

  #pragma unroll
  for (int i = 0; i < 8; ++i) {
    const int L = i * 256 + tid;
    const int r = L >> 5, c = L & 31;
    gload_lds16(&Bt[(size_t)(n0 + r) * 256 + (c ^ (r & 7)) * 8],
                &Bl[0][0] + (size_t)L * 8);
  }
  #pragma unroll
  for (int s = 0; s < 2; ++s)
    #pragma unroll
    for (int i = 0; i < 4; ++i) {
      const int L = i * 64 + lane;          // 256 chunks per slice
      const int r = L >> 2, c = L & 3;
      gload_lds16(&A[(size_t)(mw + r) * ldA + s*32 + (c ^ ((r >> 1) & 3)) * 8],
                  &Al[w][s][0][0] + (size_t)L * 8);
    }
  asm volatile("s_waitcnt vmcnt(8)" ::: "memory");
  BARRIER_RAW();

  f32x4 acc[4][4] = {};

  #pragma unroll
  for (int t = 0; t < 8; ++t) {             // K = 8 x 32, NO in-loop barriers
    if (t < 6) {
      #pragma unroll
      for (int i = 0; i < 4; ++i) {
        const int L = i * 64 + lane;
        const int r = L >> 2, c = L & 3;
        gload_lds16(&A[(size_t)(mw + r) * ldA + (t+2)*32
                       + (c ^ ((r >> 1) & 3)) * 8],
                    &Al[w][(t + 2) % 3][0][0] + (size_t)L * 8);
      }
    }
    if (t < 6)      asm volatile("s_waitcnt vmcnt(8)" ::: "memory");
    else if (t == 6) asm volatile("s_waitcnt vmcnt(4)" ::: "memory");
    else             asm volatile("s_waitcnt vmcnt(0)" ::: "memory");

    bf16x8 af[4], bfr[4];
    #pragma unroll
    for (int mi = 0; mi < 4; ++mi) {
      const int r = mi * 16 + l15;
      af[mi] = __builtin_bit_cast(bf16x8,
          *(const u16x8*)&Al[w][t % 3][r][(g ^ ((r >> 1) & 3)) * 8]);
    }
    #pragma unroll
    for (int ni = 0; ni < 4; ++ni) {
      const int r = ni * 16 + l15;
      bfr[ni] = __builtin_bit_cast(bf16x8,
          *(const u16x8*)&Bl[r][((t*4 + g) ^ (r & 7)) * 8]);
    }
    if (vmode) {
      #pragma unroll
      for (int mi = 0; mi < 4; ++mi)
        #pragma unroll
        for (int ni = 0; ni < 4; ++ni)
          acc[mi][ni] = __builtin_amdgcn_mfma_f32_16x16x32_bf16(
                            bfr[ni], af[mi], acc[mi][ni], 0, 0, 0);
    } else {
      #pragma unroll
      for (int mi = 0; mi < 4; ++mi)
        #pragma unroll
        for (int ni = 0; ni < 4; ++ni)
          acc[mi][ni] = __builtin_amdgcn_mfma_f32_16x16x32_bf16(
                            af[mi], bfr[ni], acc[mi][ni], 0, 0, 0);
    }
  }

  #pragma unroll
  for (int mi = 0; mi < 4; ++mi)
    #pragma unroll
    for (int ni = 0; ni < 4; ++ni) {
      if (!vmode) {
        const int col = n0 + ni * 16 + l15;
        const float bv = bias[col];
        #pragma unroll
        for (int r = 0; r < 4; ++r) {
          const int row = mw + mi * 16 + g * 4 + r;
          const float v = acc[mi][ni][r] + bv;
          if (OUT_MODE == 1)
            ((float*)Outp)[(size_t)row * ldOut + col] = v;
          else
            ((ushort_t*)Outp)[(size_t)row * 512 + col] = f2bf(v);
        }
      } else {
        const int hh = (n0 - 512) >> 6;
        const int m = mw + mi * 16 + l15;
        const int bb = m >> 10, ss = m & 1023;
        ushort_t* vbase =
            &Vt[(size_t)(((bb*4 + hh)*16 + (ss >> 6)) * 4096) + (ss & 63)];
        #pragma unroll
        for (int r = 0; r < 4; ++r) {
          const int nn = n0 + ni * 16 + g * 4 + r;     // 512..767
          const float v = acc[mi][ni][r] + bias[nn];
          vbase[(size_t)((nn - 512) & 63) * 64] = f2bf(v);
        }
      }
    }
}

// ---------------- kernel 2: causal flash attention (r14 + XCD-affine bh) ----
// 512 blocks, 4 waves.  NEW decode: XCD x (= lid&7) processes b in {2x,2x+1}
// (all 4 heads) -> the K/V/Q rows it reads were WRITTEN by g1's XCD x (local
// L2 first touch), and its O-writes land where g2's XCD x reads.
//   p = (lid>>3)&7 -> q-tile pair {p, 15-p};  bhi = lid>>6 in 0..7;
//   b = 2*(lid&7) + (bhi>>2);  h = bhi&3.
// K ring [3][64][64] (chunk c^(r&7)); V ring = V^T (chunk c^((r>>1)&7)).
// Counted vmcnt(4) + raw barrier per step; swapped-operand QK; in-reg P;
// mfma16 PV; exp2f softmax.
__global__ __launch_bounds__(256, 2)
void attn_kernel(ushort_t* __restrict__ qk, const ushort_t* __restrict__ Vt)
{
  __shared__ ushort_t K_lds[3][64][64];   // 24 KB ring
  __shared__ ushort_t V_lds[3][64][64];   // 24 KB ring (V^T tiles)

  const int lid = blockIdx.x;
  const int xc  = lid & 7;                // XCD under %8 round-robin
  const int p   = (lid >> 3) & 7;
  const int bhi = lid >> 6;               // 0..7
  const int b   = 2 * xc + (bhi >> 2);
  const int h   = bhi & 3;
  const int bh  = b * 4 + h;
  const int qtA = p, qtB = 15 - p;

  const int tid = threadIdx.x;
  const int lane = tid & 63;
  const int w = tid >> 6;
  const int l15 = lane & 15, g = lane >> 4;

  const size_t rowbase = (size_t)b * 1024;
  const int qc = h * 64, kc = 256 + h * 64;
  const ushort_t* Vtt = Vt + (size_t)bh * 16 * 4096;

  bf16x8 qfA[2], qfB[2];
  {
    const size_t ra = rowbase + qtA*64 + w*16 + l15;
    const size_t rb = rowbase + qtB*64 + w*16 + l15;
    #pragma unroll
    for (int ks = 0; ks < 2; ++ks) {
      qfA[ks] = __builtin_bit_cast(bf16x8,
                  *(const u16x8*)&qk[ra*512 + qc + ks*32 + g*8]);
      qfB[ks] = __builtin_bit_cast(bf16x8,
                  *(const u16x8*)&qk[rb*512 + qc + ks*32 + g*8]);
    }
  }

  f32x4 oA[4] = {}, oB[4] = {};        // O^T frags: row d=da*16+g*4+r, col q=l15
  float lsA = 0.f, lsB = 0.f;
  const int qgA = qtA*64 + w*16 + l15;
  const int qgB = qtB*64 + w*16 + l15;

  auto stage = [&](int bi, int kt) {   // 4 gload/thread
    const int kv0 = kt * 64;
    const ushort_t* vtile = Vtt + kt * 4096;
    #pragma unroll
    for (int ri = 0; ri < 2; ++ri) {
      const int L = ri*256 + tid;      // 16B-chunk 0..511
      const int r = L >> 3;
      gload_lds16(&qk[(rowbase + kv0 + r)*512 + kc + ((L & 7) ^ (r & 7))*8],
                  &K_lds[bi][0][0] + (size_t)L*8);
      gload_lds16(&vtile[r*64 + ((L & 7) ^ ((r >> 1) & 7))*8],
                  &V_lds[bi][0][0] + (size_t)L*8);
    }
  };

  stage(0, 0);
  stage(1, 1);                          // qtB >= 8, always exists
  asm volatile("s_waitcnt vmcnt(4)" ::: "memory");
  BARRIER_RAW();

  for (int kt = 0; kt <= qtB; ++kt) {
    const int cur = kt % 3;
    stage((kt + 2) % 3, (kt + 2 <= qtB) ? kt + 2 : qtB);

    // K frags (A-operand): row kv=ni*16+l15, k(d)=ks*32+g*8+j
    bf16x8 kf[2][4];
    #pragma unroll
    for (int ks = 0; ks < 2; ++ks)
      #pragma unroll
      for (int ni = 0; ni < 4; ++ni) {
        const int row = ni*16 + l15;
        kf[ks][ni] = __builtin_bit_cast(bf16x8,
            *(const u16x8*)&K_lds[cur][row][(((ks*4 + g) ^ (row & 7))) * 8]);
      }
    // V^T frags for PV 16x16x16 (A-operand): row d=da*16+l15, k(kv)=ni*16+g*4+j
    bf16x4 vf[4][4];
    #pragma unroll
    for (int ni = 0; ni < 4; ++ni)
      #pragma unroll
      for (int da = 0; da < 4; ++da) {
        const int row = da*16 + l15;
        const int phys = (ni*2 + (g >> 1)) ^ ((row >> 1) & 7);
        vf[ni][da] = __builtin_bit_cast(bf16x4,
            *(const u16x4*)&V_lds[cur][row][phys*8 + (g & 1)*4]);
      }

    const int kv0 = kt * 64;
    const int g4 = g * 4;

    auto tile_step = [&](const bf16x8 (&qf)[2], f32x4 (&o)[4], float &ls,
                         int qg, bool diag) {
      f32x4 s[4] = {};
      #pragma unroll
      for (int ks = 0; ks < 2; ++ks)
        #pragma unroll
        for (int ni = 0; ni < 4; ++ni)
          s[ni] = __builtin_amdgcn_mfma_f32_16x16x32_bf16(kf[ks][ni], qf[ks],
                                                          s[ni], 0, 0, 0);
      bf16x4 pn[4];
      #pragma unroll
      for (int ni = 0; ni < 4; ++ni)
        #pragma unroll
        for (int r = 0; r < 4; ++r) {
          // exp(s/8 - 10) = exp2(s*log2e/8 - 10*log2e)
          float e = exp2f(fmaf(s[ni][r], 0.18033688011112042f,
                               -14.426950408889634f));
          if (diag) e = (kv0 + ni*16 + g4 + r <= qg) ? e : 0.0f;
          ls += e;
          pn[ni][r] = (__bf16)e;
        }
      #pragma unroll
      for (int ni = 0; ni < 4; ++ni)
        #pragma unroll
        for (int da = 0; da < 4; ++da)
          o[da] = mfma16(vf[ni][da], pn[ni], o[da]);
    };

    tile_step(qfB, oB, lsB, qgB, kt == qtB);
    if (kt <= qtA) tile_step(qfA, oA, lsA, qgA, kt == qtA);

    asm volatile("s_waitcnt vmcnt(4)" ::: "memory");
    BARRIER_RAW();
  }

  asm volatile("s_nop 7\n\ts_nop 7" :::);

  lsA += __shfl_xor(lsA, 16); lsA += __shfl_xor(lsA, 32);
  lsB += __shfl_xor(lsB, 16); lsB += __shfl_xor(lsB, 32);
  const float invA = 1.f / lsA;
  const float invB = 1.f / lsB;

  {
    const size_t rowA = rowbase + (size_t)qgA;
    const size_t rowB = rowbase + (size_t)qgB;
    #pragma unroll
    for (int da = 0; da < 4; ++da) {
      u16x4 ovA, ovB;
      #pragma unroll
      for (int r = 0; r < 4; ++r) {
        ovA[r] = f2bf(oA[da][r] * invA);
        ovB[r] = f2bf(oB[da][r] * invB);
      }
      *(u16x4*)&qk[rowA*512 + qc + da*16 + g*4] = ovA;
      *(u16x4*)&qk[rowB*512 + qc + da*16 + g*4] = ovB;
    }
  }
}

// ---------------- launcher --------------------------------------------------
extern "C" void kernel_launch(void* const* d_in, const int* in_sizes, int n_in,
                              void* d_out, int out_size, void* d_ws, size_t ws_size,
                              hipStream_t stream)
{
  const float* x     = (const float*)d_in[0];
  const float* W_qkv = (const float*)d_in[1];
  const float* b_qkv = (const float*)d_in[2];
  const float* W_out = (const float*)d_in[3];
  const float* b_out = (const float*)d_in[4];
  float* out = (float*)d_out;

  char* ws = (char*)d_ws;
  ushort_t* WqT = (ushort_t*)ws;                         // [768][256]
  ushort_t* WoT = (ushort_t*)(ws + 393216);              // [256][256]
  ushort_t* qk  = (ushort_t*)(ws + 524288);              // [16384][512]
  ushort_t* Vt  = (ushort_t*)(ws + 17301504);            // [64][16][64][64]
  ushort_t* xb  = (ushort_t*)(ws + 25690112);            // [16384][256]

  convert_all<<<dim3(2112), dim3(256), 0, stream>>>(x, W_qkv, W_out, xb, WqT, WoT);
  // QKV projection: GEMM v4, 768 blocks (XCD x -> batches {2x,2x+1})
  gemm_bias<0, 12><<<dim3(768), dim3(256), 0, stream>>>(
      xb, 256, WqT, b_qkv, qk, 512, Vt);
  // causal flash attention (XCD-affine bh decode)
  attn_kernel<<<dim3(512), dim3(256), 0, stream>>>(qk, Vt);
  // output projection: GEMM v4, 256 blocks
  gemm_bias<1, 4><<<dim3(256), dim3(256), 0, stream>>>(
      qk, 512, WoT, b_out, out, 256, nullptr);
}

// Round 17
// 63.413 us; speedup vs baseline: 1.0089x; 1.0089x over previous
//
#include <hip/hip_runtime.h>

// Attention_55336358642806: x@W_qkv+b -> 4-head causal attention -> @W_out+b
// B=16 S=1024 E=256 H=4 D=64.  All-MFMA bf16 pipeline, fp32 accumulation.
//
// r17: attn pipeline DEPTH 2->3 tiles ahead (4-deep rings, vmcnt(8)).
// Mechanism being tested: kernel-boundary L2 flush (required for cross-XCD
// visibility) forces attn to read qk/Vt from L3 (~700-1000cy); the old
// 3-ring's wait covered only ~1 iteration -> exposed latency every step.
// 4-ring covers ~2 iterations.  Everything else identical to r16.
//
// ws layout (bytes):
//   [0,        393216)   W_qkvT bf16 [768][256]
//   [393216,   524288)   W_outT bf16 [256][256]
//   [524288, 17301504)   qk     bf16 [16384][512]  (Q cols 0..255, K 256..511;
//                                                   attn out overwrites Q cols)
//   [17301504,25690112)  Vt     bf16 [64 bh][16 kvt][64 d][64 kv]
//   [25690112,34078720)  xb     bf16 [16384][256]

typedef unsigned short ushort_t;
typedef __bf16 bf16x8 __attribute__((ext_vector_type(8)));
typedef __bf16 bf16x4 __attribute__((ext_vector_type(4)));
typedef unsigned short u16x8 __attribute__((ext_vector_type(8)));
typedef unsigned short u16x4 __attribute__((ext_vector_type(4)));
typedef float f32x4 __attribute__((ext_vector_type(4)));
typedef short s16x4 __attribute__((ext_vector_type(4)));

__device__ __forceinline__ ushort_t f2bf(float f) {
  __bf16 h = (__bf16)f;
  return __builtin_bit_cast(ushort_t, h);
}

__device__ __forceinline__ void gload_lds16(const ushort_t* g, ushort_t* l) {
  __builtin_amdgcn_global_load_lds(
      (const __attribute__((address_space(1))) unsigned int*)g,
      (__attribute__((address_space(3))) unsigned int*)l, 16, 0, 0);
}

#define BARRIER_RAW() do { __builtin_amdgcn_s_barrier(); \
                           __builtin_amdgcn_sched_barrier(0); } while (0)

__device__ __forceinline__ f32x4 mfma16(bf16x4 a, bf16x4 b, f32x4 c) {
#if __has_builtin(__builtin_amdgcn_mfma_f32_16x16x16bf16_1k)
  return __builtin_amdgcn_mfma_f32_16x16x16bf16_1k(
      __builtin_bit_cast(s16x4, a), __builtin_bit_cast(s16x4, b), c, 0, 0, 0);
#elif __has_builtin(__builtin_amdgcn_mfma_f32_16x16x16_bf16)
  return __builtin_amdgcn_mfma_f32_16x16x16_bf16(a, b, c, 0, 0, 0);
#else
  f32x4 d = c;
  asm volatile("v_mfma_f32_16x16x16_bf16 %0, %1, %2, %0"
               : "+v"(d) : "v"(a), "v"(b));
  return d;
#endif
}

// ------------- kernel 0: convert x->bf16 + transpose weights ----------------
__global__ __launch_bounds__(256)
void convert_all(const float* __restrict__ x,
                 const float* __restrict__ Wq, const float* __restrict__ Wo,
                 ushort_t* __restrict__ xb,
                 ushort_t* __restrict__ WqT, ushort_t* __restrict__ WoT)
{
  int blk = blockIdx.x;
  if (blk < 2048) {                 // x: 8 floats/thread, coalesced, XCD-affine
    const int xc = blk & 7, j = blk >> 3;
    const size_t base = (size_t)xc * 524288 + (size_t)j * 2048 + threadIdx.x * 8;
    float4 v0 = *(const float4*)&x[base];
    float4 v1 = *(const float4*)&x[base + 4];
    u16x8 ov;
    ov[0]=f2bf(v0.x); ov[1]=f2bf(v0.y); ov[2]=f2bf(v0.z); ov[3]=f2bf(v0.w);
    ov[4]=f2bf(v1.x); ov[5]=f2bf(v1.y); ov[6]=f2bf(v1.z); ov[7]=f2bf(v1.w);
    *(u16x8*)&xb[base] = ov;
    return;
  }
  blk -= 2048;                      // weights: LDS-tile transpose, coalesced
  __shared__ float t[64][65];
  const float* src; ushort_t* dst; int ld_src, k0, n0;
  if (blk < 48) { src = Wq; dst = WqT; ld_src = 768;
                  k0 = (blk / 12) * 64; n0 = (blk % 12) * 64; }
  else { blk -= 48; src = Wo; dst = WoT; ld_src = 256;
         k0 = (blk / 4) * 64; n0 = (blk % 4) * 64; }
  const int tr = threadIdx.x >> 6, tc = threadIdx.x & 63;
  #pragma unroll
  for (int i = 0; i < 16; ++i) {
    const int r = i * 4 + tr;
    t[r][tc] = src[(size_t)(k0 + r) * ld_src + n0 + tc];
  }
  __syncthreads();
  #pragma unroll
  for (int i = 0; i < 16; ++i) {
    const int r = i * 4 + tr;
    dst[(size_t)(n0 + r) * 256 + k0 + tc] = f2bf(t[tc][r]);
  }
}

// ---------------- GEMM v4 (r9/r14 measured-best, unchanged) -----------------
template<int OUT_MODE, int NB>            // OUT_MODE: 0=qkv split, 1=f32
__global__ __launch_bounds__(256, 2)
void gemm_bias(const ushort_t* __restrict__ A, int ldA,
               const ushort_t* __restrict__ Bt,
               const float* __restrict__ bias,
               void* __restrict__ Outp, int ldOut,
               ushort_t* __restrict__ Vt)
{
  __shared__ ushort_t Bl[64][256];          // 32 KB; 16B-chunk c at c^(r&7)
  __shared__ ushort_t Al[4][3][64][32];     // 48 KB; chunk c at c^((r>>1)&3)

  const int tid = threadIdx.x;
  const int lane = tid & 63;
  const int w  = tid >> 6;
  const int l15 = lane & 15, g = lane >> 4;

  const int nwg = NB * 64;
  const int inner = (int)blockIdx.x % nwg;
  const int chunkXCD = nwg >> 3;
  const int gidx = (inner & 7) * chunkXCD + (inner >> 3);
  const int n0 = (gidx % NB) * 64;
  const int mBase = (gidx / NB) * 256;
  const int mw = mBase + w * 64;            // this wave's 64 rows
  const bool vmode = (OUT_MODE == 0) && (n0 >= 512);

  #pragma unroll
  for (int i = 0; i < 8; ++i) {
    const int L = i * 256 + tid;
    const int r = L >> 5, c = L & 31;
    gload_lds16(&Bt[(size_t)(n0 + r) * 256 + (c ^ (r & 7)) * 8],
                &Bl[0][0] + (size_t)L * 8);
  }
  #pragma unroll
  for (int s = 0; s < 2; ++s)
    #pragma unroll
    for (int i = 0; i < 4; ++i) {
      const int L = i * 64 + lane;          // 256 chunks per slice
      const int r = L >> 2, c = L & 3;
      gload_lds16(&A[(size_t)(mw + r) * ldA + s*32 + (c ^ ((r >> 1) & 3)) * 8],
                  &Al[w][s][0][0] + (size_t)L * 8);
    }
  asm volatile("s_waitcnt vmcnt(8)" ::: "memory");
  BARRIER_RAW();

  f32x4 acc[4][4] = {};

  #pragma unroll
  for (int t = 0; t < 8; ++t) {             // K = 8 x 32, NO in-loop barriers
    if (t < 6) {
      #pragma unroll
      for (int i = 0; i < 4; ++i) {
        const int L = i * 64 + lane;
        const int r = L >> 2, c = L & 3;
        gload_lds16(&A[(size_t)(mw + r) * ldA + (t+2)*32
                       + (c ^ ((r >> 1) & 3)) * 8],
                    &Al[w][(t + 2) % 3][0][0] + (size_t)L * 8);
      }
    }
    if (t < 6)      asm volatile("s_waitcnt vmcnt(8)" ::: "memory");
    else if (t == 6) asm volatile("s_waitcnt vmcnt(4)" ::: "memory");
    else             asm volatile("s_waitcnt vmcnt(0)" ::: "memory");

    bf16x8 af[4], bfr[4];
    #pragma unroll
    for (int mi = 0; mi < 4; ++mi) {
      const int r = mi * 16 + l15;
      af[mi] = __builtin_bit_cast(bf16x8,
          *(const u16x8*)&Al[w][t % 3][r][(g ^ ((r >> 1) & 3)) * 8]);
    }
    #pragma unroll
    for (int ni = 0; ni < 4; ++ni) {
      const int r = ni * 16 + l15;
      bfr[ni] = __builtin_bit_cast(bf16x8,
          *(const u16x8*)&Bl[r][((t*4 + g) ^ (r & 7)) * 8]);
    }
    if (vmode) {
      #pragma unroll
      for (int mi = 0; mi < 4; ++mi)
        #pragma unroll
        for (int ni = 0; ni < 4; ++ni)
          acc[mi][ni] = __builtin_amdgcn_mfma_f32_16x16x32_bf16(
                            bfr[ni], af[mi], acc[mi][ni], 0, 0, 0);
    } else {
      #pragma unroll
      for (int mi = 0; mi < 4; ++mi)
        #pragma unroll
        for (int ni = 0; ni < 4; ++ni)
          acc[mi][ni] = __builtin_amdgcn_mfma_f32_16x16x32_bf16(
                            af[mi], bfr[ni], acc[mi][ni], 0, 0, 0);
    }
  }

  #pragma unroll
  for (int mi = 0; mi < 4; ++mi)
    #pragma unroll
    for (int ni = 0; ni < 4; ++ni) {
      if (!vmode) {
        const int col = n0 + ni * 16 + l15;
        const float bv = bias[col];
        #pragma unroll
        for (int r = 0; r < 4; ++r) {
          const int row = mw + mi * 16 + g * 4 + r;
          const float v = acc[mi][ni][r] + bv;
          if (OUT_MODE == 1)
            ((float*)Outp)[(size_t)row * ldOut + col] = v;
          else
            ((ushort_t*)Outp)[(size_t)row * 512 + col] = f2bf(v);
        }
      } else {
        const int hh = (n0 - 512) >> 6;
        const int m = mw + mi * 16 + l15;
        const int bb = m >> 10, ss = m & 1023;
        ushort_t* vbase =
            &Vt[(size_t)(((bb*4 + hh)*16 + (ss >> 6)) * 4096) + (ss & 63)];
        #pragma unroll
        for (int r = 0; r < 4; ++r) {
          const int nn = n0 + ni * 16 + g * 4 + r;     // 512..767
          const float v = acc[mi][ni][r] + bias[nn];
          vbase[(size_t)((nn - 512) & 63) * 64] = f2bf(v);
        }
      }
    }
}

// ---------------- kernel 2: causal flash attention (r16 + 4-deep rings) -----
// 512 blocks, 4 waves.  XCD-affine decode (r16).  Prefetch distance 3:
// rings K[4]/V[4] (64KB), prologue stages tiles 0,1,2; steady state 12 loads
// in flight; end-of-iter vmcnt(8) -> tile kt+1 landed, issued TWO iterations
// earlier (~2x the L3-latency cover of the 3-ring).
__global__ __launch_bounds__(256, 2)
void attn_kernel(ushort_t* __restrict__ qk, const ushort_t* __restrict__ Vt)
{
  __shared__ ushort_t K_lds[4][64][64];   // 32 KB ring
  __shared__ ushort_t V_lds[4][64][64];   // 32 KB ring (V^T tiles)

  const int lid = blockIdx.x;
  const int xc  = lid & 7;                // XCD under %8 round-robin
  const int p   = (lid >> 3) & 7;
  const int bhi = lid >> 6;               // 0..7
  const int b   = 2 * xc + (bhi >> 2);
  const int h   = bhi & 3;
  const int bh  = b * 4 + h;
  const int qtA = p, qtB = 15 - p;

  const int tid = threadIdx.x;
  const int lane = tid & 63;
  const int w = tid >> 6;
  const int l15 = lane & 15, g = lane >> 4;

  const size_t rowbase = (size_t)b * 1024;
  const int qc = h * 64, kc = 256 + h * 64;
  const ushort_t* Vtt = Vt + (size_t)bh * 16 * 4096;

  bf16x8 qfA[2], qfB[2];
  {
    const size_t ra = rowbase + qtA*64 + w*16 + l15;
    const size_t rb = rowbase + qtB*64 + w*16 + l15;
    #pragma unroll
    for (int ks = 0; ks < 2; ++ks) {
      qfA[ks] = __builtin_bit_cast(bf16x8,
                  *(const u16x8*)&qk[ra*512 + qc + ks*32 + g*8]);
      qfB[ks] = __builtin_bit_cast(bf16x8,
                  *(const u16x8*)&qk[rb*512 + qc + ks*32 + g*8]);
    }
  }

  f32x4 oA[4] = {}, oB[4] = {};        // O^T frags: row d=da*16+g*4+r, col q=l15
  float lsA = 0.f, lsB = 0.f;
  const int qgA = qtA*64 + w*16 + l15;
  const int qgB = qtB*64 + w*16 + l15;

  auto stage = [&](int bi, int kt) {   // 4 gload/thread
    const int kv0 = kt * 64;
    const ushort_t* vtile = Vtt + kt * 4096;
    #pragma unroll
    for (int ri = 0; ri < 2; ++ri) {
      const int L = ri*256 + tid;      // 16B-chunk 0..511
      const int r = L >> 3;
      gload_lds16(&qk[(rowbase + kv0 + r)*512 + kc + ((L & 7) ^ (r & 7))*8],
                  &K_lds[bi][0][0] + (size_t)L*8);
      gload_lds16(&vtile[r*64 + ((L & 7) ^ ((r >> 1) & 7))*8],
                  &V_lds[bi][0][0] + (size_t)L*8);
    }
  };

  // prologue: tiles 0,1,2 in flight (qtB >= 8, all exist)
  stage(0, 0);
  stage(1, 1);
  stage(2, 2);
  asm volatile("s_waitcnt vmcnt(8)" ::: "memory");   // tile 0 landed
  BARRIER_RAW();

  for (int kt = 0; kt <= qtB; ++kt) {
    const int cur = kt & 3;
    // stage kt+3 (tail: dup of last tile into the dead slot (kt-1)&3)
    stage((kt + 3) & 3, (kt + 3 <= qtB) ? kt + 3 : qtB);

    // K frags (A-operand): row kv=ni*16+l15, k(d)=ks*32+g*8+j
    bf16x8 kf[2][4];
    #pragma unroll
    for (int ks = 0; ks < 2; ++ks)
      #pragma unroll
      for (int ni = 0; ni < 4; ++ni) {
        const int row = ni*16 + l15;
        kf[ks][ni] = __builtin_bit_cast(bf16x8,
            *(const u16x8*)&K_lds[cur][row][(((ks*4 + g) ^ (row & 7))) * 8]);
      }
    // V^T frags for PV 16x16x16 (A-operand): row d=da*16+l15, k(kv)=ni*16+g*4+j
    bf16x4 vf[4][4];
    #pragma unroll
    for (int ni = 0; ni < 4; ++ni)
      #pragma unroll
      for (int da = 0; da < 4; ++da) {
        const int row = da*16 + l15;
        const int phys = (ni*2 + (g >> 1)) ^ ((row >> 1) & 7);
        vf[ni][da] = __builtin_bit_cast(bf16x4,
            *(const u16x4*)&V_lds[cur][row][phys*8 + (g & 1)*4]);
      }

    const int kv0 = kt * 64;
    const int g4 = g * 4;

    auto tile_step = [&](const bf16x8 (&qf)[2], f32x4 (&o)[4], float &ls,
                         int qg, bool diag) {
      f32x4 s[4] = {};
      #pragma unroll
      for (int ks = 0; ks < 2; ++ks)
        #pragma unroll
        for (int ni = 0; ni < 4; ++ni)
          s[ni] = __builtin_amdgcn_mfma_f32_16x16x32_bf16(kf[ks][ni], qf[ks],
                                                          s[ni], 0, 0, 0);
      bf16x4 pn[4];
      #pragma unroll
      for (int ni = 0; ni < 4; ++ni)
        #pragma unroll
        for (int r = 0; r < 4; ++r) {
          // exp(s/8 - 10) = exp2(s*log2e/8 - 10*log2e)
          float e = exp2f(fmaf(s[ni][r], 0.18033688011112042f,
                               -14.426950408889634f));
          if (diag) e = (kv0 + ni*16 + g4 + r <= qg) ? e : 0.0f;
          ls += e;
          pn[ni][r] = (__bf16)e;
        }
      #pragma unroll
      for (int ni = 0; ni < 4; ++ni)
        #pragma unroll
        for (int da = 0; da < 4; ++da)
          o[da] = mfma16(vf[ni][da], pn[ni], o[da]);
    };

    tile_step(qfB, oB, lsB, qgB, kt == qtB);
    if (kt <= qtA) tile_step(qfA, oA, lsA, qgA, kt == qtA);

    asm volatile("s_waitcnt vmcnt(8)" ::: "memory");  // tile kt+1 landed
    BARRIER_RAW();
  }

  asm volatile("s_nop 7\n\ts_nop 7" :::);

  lsA += __shfl_xor(lsA, 16); lsA += __shfl_xor(lsA, 32);
  lsB += __shfl_xor(lsB, 16); lsB += __shfl_xor(lsB, 32);
  const float invA = 1.f / lsA;
  const float invB = 1.f / lsB;

  {
    const size_t rowA = rowbase + (size_t)qgA;
    const size_t rowB = rowbase + (size_t)qgB;
    #pragma unroll
    for (int da = 0; da < 4; ++da) {
      u16x4 ovA, ovB;
      #pragma unroll
      for (int r = 0; r < 4; ++r) {
        ovA[r] = f2bf(oA[da][r] * invA);
        ovB[r] = f2bf(oB[da][r] * invB);
      }
      *(u16x4*)&qk[rowA*512 + qc + da*16 + g*4] = ovA;
      *(u16x4*)&qk[rowB*512 + qc + da*16 + g*4] = ovB;
    }
  }
}

// ---------------- launcher --------------------------------------------------
extern "C" void kernel_launch(void* const* d_in, const int* in_sizes, int n_in,
                              void* d_out, int out_size, void* d_ws, size_t ws_size,
                              hipStream_t stream)
{
  const float* x     = (const float*)d_in[0];
  const float* W_qkv = (const float*)d_in[1];
  const float* b_qkv = (const float*)d_in[2];
  const float* W_out = (const float*)d_in[3];
  const float* b_out = (const float*)d_in[4];
  float* out = (float*)d_out;

  char* ws = (char*)d_ws;
  ushort_t* WqT = (ushort_t*)ws;                         // [768][256]
  ushort_t* WoT = (ushort_t*)(ws + 393216);              // [256][256]
  ushort_t* qk  = (ushort_t*)(ws + 524288);              // [16384][512]
  ushort_t* Vt  = (ushort_t*)(ws + 17301504);            // [64][16][64][64]
  ushort_t* xb  = (ushort_t*)(ws + 25690112);            // [16384][256]

  convert_all<<<dim3(2112), dim3(256), 0, stream>>>(x, W_qkv, W_out, xb, WqT, WoT);
  // QKV projection: GEMM v4, 768 blocks
  gemm_bias<0, 12><<<dim3(768), dim3(256), 0, stream>>>(
      xb, 256, WqT, b_qkv, qk, 512, Vt);
  // causal flash attention (4-deep rings, prefetch distance 3)
  attn_kernel<<<dim3(512), dim3(256), 0, stream>>>(qk, Vt);
  // output projection: GEMM v4, 256 blocks
  gemm_bias<1, 4><<<dim3(256), dim3(256), 0, stream>>>(
      qk, 512, WoT, b_out, out, 256, nullptr);
}

// Round 18
// 62.794 us; speedup vs baseline: 1.0189x; 1.0099x over previous
//
#include <hip/hip_runtime.h>

// Attention_55336358642806: x@W_qkv+b -> 4-head causal attention -> @W_out+b
// B=16 S=1024 E=256 H=4 D=64.  All-MFMA bf16 pipeline, fp32 accumulation.
//
// r18: ELIMINATE the x-convert pass.  Budget model (corrected): conv ~12us
// (67MB fp32 HBM read) + g1 ~14 + attn ~17 + g2 ~12 (67MB fp32 HBM write)
// ~= the stubborn 63us.  g1 becomes r12's v5 (fp32 A consumed directly,
// reg-staged convert; correctness-proven r12); conv shrinks to weights-only;
// attn = r17 verbatim; g2 = r14's v4 verbatim.
//
// ws layout (bytes):
//   [0,        393216)   W_qkvT bf16 [768][256]
//   [393216,   524288)   W_outT bf16 [256][256]
//   [524288, 17301504)   qk     bf16 [16384][512]  (Q cols 0..255, K 256..511;
//                                                   attn out overwrites Q cols)
//   [17301504,25690112)  Vt     bf16 [64 bh][16 kvt][64 d][64 kv]

typedef unsigned short ushort_t;
typedef __bf16 bf16x8 __attribute__((ext_vector_type(8)));
typedef __bf16 bf16x4 __attribute__((ext_vector_type(4)));
typedef unsigned short u16x8 __attribute__((ext_vector_type(8)));
typedef unsigned short u16x4 __attribute__((ext_vector_type(4)));
typedef float f32x4 __attribute__((ext_vector_type(4)));
typedef short s16x4 __attribute__((ext_vector_type(4)));

__device__ __forceinline__ ushort_t f2bf(float f) {
  __bf16 h = (__bf16)f;
  return __builtin_bit_cast(ushort_t, h);
}

__device__ __forceinline__ void gload_lds16(const ushort_t* g, ushort_t* l) {
  __builtin_amdgcn_global_load_lds(
      (const __attribute__((address_space(1))) unsigned int*)g,
      (__attribute__((address_space(3))) unsigned int*)l, 16, 0, 0);
}

#define BARRIER_RAW() do { __builtin_amdgcn_s_barrier(); \
                           __builtin_amdgcn_sched_barrier(0); } while (0)

__device__ __forceinline__ f32x4 mfma16(bf16x4 a, bf16x4 b, f32x4 c) {
#if __has_builtin(__builtin_amdgcn_mfma_f32_16x16x16bf16_1k)
  return __builtin_amdgcn_mfma_f32_16x16x16bf16_1k(
      __builtin_bit_cast(s16x4, a), __builtin_bit_cast(s16x4, b), c, 0, 0, 0);
#elif __has_builtin(__builtin_amdgcn_mfma_f32_16x16x16_bf16)
  return __builtin_amdgcn_mfma_f32_16x16x16_bf16(a, b, c, 0, 0, 0);
#else
  f32x4 d = c;
  asm volatile("v_mfma_f32_16x16x16_bf16 %0, %1, %2, %0"
               : "+v"(d) : "v"(a), "v"(b));
  return d;
#endif
}

// ------------- kernel 0: weight transpose+convert only (64 blocks) ----------
__global__ __launch_bounds__(256)
void convert_wt(const float* __restrict__ Wq, const float* __restrict__ Wo,
                ushort_t* __restrict__ WqT, ushort_t* __restrict__ WoT)
{
  __shared__ float t[64][65];
  int blk = blockIdx.x;
  const float* src; ushort_t* dst; int ld_src, k0, n0;
  if (blk < 48) { src = Wq; dst = WqT; ld_src = 768;
                  k0 = (blk / 12) * 64; n0 = (blk % 12) * 64; }
  else { blk -= 48; src = Wo; dst = WoT; ld_src = 256;
         k0 = (blk / 4) * 64; n0 = (blk % 4) * 64; }
  const int tr = threadIdx.x >> 6, tc = threadIdx.x & 63;
  #pragma unroll
  for (int i = 0; i < 16; ++i) {
    const int r = i * 4 + tr;
    t[r][tc] = src[(size_t)(k0 + r) * ld_src + n0 + tc];
  }
  __syncthreads();
  #pragma unroll
  for (int i = 0; i < 16; ++i) {
    const int r = i * 4 + tr;
    dst[(size_t)(n0 + r) * 256 + k0 + tc] = f2bf(t[tc][r]);
  }
}

// ---------------- GEMM v5 (r12, fused fp32-A convert) -----------------------
// Block: 4 waves, tile 128M x 64N; wave w owns rows [mBase+w*32, +32).
// Bl resident (ONE barrier).  A: per-wave 2-buf reg-staged (fp32 cvt fused),
// counted per-wave vmcnt, NO in-loop barriers, 8 unrolled steps.
template<int A_F32, int OUT_MODE, int NB>  // OUT_MODE: 0=qkv split, 1=f32
__global__ __launch_bounds__(256, 3)
void gemm_v5(const void* __restrict__ Ap, int ldA,
             const ushort_t* __restrict__ Bt,
             const float* __restrict__ bias,
             void* __restrict__ Outp, int ldOut,
             ushort_t* __restrict__ Vt)
{
  __shared__ ushort_t Bl[64][256];          // 32 KB; 16B-chunk c at c^(r&7)
  __shared__ ushort_t Al[4][2][32][32];     // 16 KB; slot p holds chunk p^((r>>1)&3)

  const int tid = threadIdx.x;
  const int lane = tid & 63;
  const int w  = tid >> 6;
  const int l15 = lane & 15, g = lane >> 4;

  const int nwg = NB * 128;
  const int inner = (int)blockIdx.x;
  const int chunkXCD = nwg >> 3;
  const int gidx = (inner & 7) * chunkXCD + (inner >> 3);
  const int n0 = (gidx % NB) * 64;
  const int mBase = (gidx / NB) * 128;
  const int mw = mBase + w * 32;            // this wave's 32 rows
  const bool vmode = (OUT_MODE == 0) && (n0 >= 512);

  const int ar0 = lane >> 2, ar1 = 16 + ar0, ac = lane & 3;
  const int acc0 = ac ^ ((ar0 >> 1) & 3);
  const int acc1 = ac ^ ((ar1 >> 1) & 3);

  auto loadA = [&](int t, float4& f0, float4& f1, float4& f2, float4& f3) {
    if constexpr (A_F32) {
      const float* Af = (const float*)Ap;
      const float* p0 = &Af[(size_t)(mw + ar0) * ldA + t*32 + acc0*8];
      const float* p1 = &Af[(size_t)(mw + ar1) * ldA + t*32 + acc1*8];
      f0 = *(const float4*)p0; f1 = *(const float4*)(p0 + 4);
      f2 = *(const float4*)p1; f3 = *(const float4*)(p1 + 4);
    } else {
      const ushort_t* Ab = (const ushort_t*)Ap;
      f0 = *(const float4*)&Ab[(size_t)(mw + ar0) * ldA + t*32 + acc0*8];
      f2 = *(const float4*)&Ab[(size_t)(mw + ar1) * ldA + t*32 + acc1*8];
    }
  };
  auto writeA = [&](int buf, const float4& f0, const float4& f1,
                    const float4& f2, const float4& f3) {
    u16x8 u0, u1;
    if constexpr (A_F32) {
      u0[0]=f2bf(f0.x); u0[1]=f2bf(f0.y); u0[2]=f2bf(f0.z); u0[3]=f2bf(f0.w);
      u0[4]=f2bf(f1.x); u0[5]=f2bf(f1.y); u0[6]=f2bf(f1.z); u0[7]=f2bf(f1.w);
      u1[0]=f2bf(f2.x); u1[1]=f2bf(f2.y); u1[2]=f2bf(f2.z); u1[3]=f2bf(f2.w);
      u1[4]=f2bf(f3.x); u1[5]=f2bf(f3.y); u1[6]=f2bf(f3.z); u1[7]=f2bf(f3.w);
    } else {
      u0 = __builtin_bit_cast(u16x8, f0);
      u1 = __builtin_bit_cast(u16x8, f2);
    }
    *(u16x8*)&Al[w][buf][ar0][ac*8] = u0;
    *(u16x8*)&Al[w][buf][ar1][ac*8] = u1;
  };
  #define VMCNT_A() do { if constexpr (A_F32) \
      asm volatile("s_waitcnt vmcnt(4)" ::: "memory"); \
    else asm volatile("s_waitcnt vmcnt(2)" ::: "memory"); } while (0)

  #pragma unroll
  for (int i = 0; i < 8; ++i) {
    const int L = i * 256 + tid;
    const int r = L >> 5, c = L & 31;
    gload_lds16(&Bt[(size_t)(n0 + r) * 256 + (c ^ (r & 7)) * 8],
                &Bl[0][0] + (size_t)L * 8);
  }
  float4 a0, a1, a2, a3, b0, b1, b2, b3;
  loadA(0, a0, a1, a2, a3);
  loadA(1, b0, b1, b2, b3);
  VMCNT_A();
  writeA(0, a0, a1, a2, a3);
  asm volatile("s_waitcnt lgkmcnt(0)" ::: "memory");
  BARRIER_RAW();

  f32x4 acc[2][4] = {};

  #pragma unroll
  for (int t = 0; t < 8; ++t) {              // NO in-loop barriers
    if (t < 6) {
      if (t & 1) loadA(t + 2, b0, b1, b2, b3);
      else       loadA(t + 2, a0, a1, a2, a3);
    }
    bf16x8 af[2], bfr[4];
    #pragma unroll
    for (int mi = 0; mi < 2; ++mi) {
      const int r = mi * 16 + l15;
      af[mi] = __builtin_bit_cast(bf16x8,
          *(const u16x8*)&Al[w][t & 1][r][(g ^ ((r >> 1) & 3)) * 8]);
    }
    #pragma unroll
    for (int ni = 0; ni < 4; ++ni) {
      const int r = ni * 16 + l15;
      bfr[ni] = __builtin_bit_cast(bf16x8,
          *(const u16x8*)&Bl[r][((t*4 + g) ^ (r & 7)) * 8]);
    }
    if (vmode) {
      #pragma unroll
      for (int mi = 0; mi < 2; ++mi)
        #pragma unroll
        for (int ni = 0; ni < 4; ++ni)
          acc[mi][ni] = __builtin_amdgcn_mfma_f32_16x16x32_bf16(
                            bfr[ni], af[mi], acc[mi][ni], 0, 0, 0);
    } else {
      #pragma unroll
      for (int mi = 0; mi < 2; ++mi)
        #pragma unroll
        for (int ni = 0; ni < 4; ++ni)
          acc[mi][ni] = __builtin_amdgcn_mfma_f32_16x16x32_bf16(
                            af[mi], bfr[ni], acc[mi][ni], 0, 0, 0);
    }
    if (t < 6) VMCNT_A();
    else if (t == 6) asm volatile("s_waitcnt vmcnt(0)" ::: "memory");
    if (t < 7) {
      if (t & 1) writeA((t + 1) & 1, a0, a1, a2, a3);
      else       writeA((t + 1) & 1, b0, b1, b2, b3);
      asm volatile("s_waitcnt lgkmcnt(0)" ::: "memory");
    }
  }

  #pragma unroll
  for (int mi = 0; mi < 2; ++mi)
    #pragma unroll
    for (int ni = 0; ni < 4; ++ni) {
      if (!vmode) {
        const int col = n0 + ni * 16 + l15;
        const float bv = bias[col];
        #pragma unroll
        for (int r = 0; r < 4; ++r) {
          const int row = mw + mi * 16 + g * 4 + r;
          const float v = acc[mi][ni][r] + bv;
          if (OUT_MODE == 1)
            ((float*)Outp)[(size_t)row * ldOut + col] = v;
          else
            ((ushort_t*)Outp)[(size_t)row * 512 + col] = f2bf(v);
        }
      } else {
        const int hh = (n0 - 512) >> 6;
        const int m = mw + mi * 16 + l15;
        const int bb = m >> 10, ss = m & 1023;
        ushort_t* vbase =
            &Vt[(size_t)(((bb*4 + hh)*16 + (ss >> 6)) * 4096) + (ss & 63)];
        #pragma unroll
        for (int r = 0; r < 4; ++r) {
          const int nn = n0 + ni * 16 + g * 4 + r;     // 512..767
          const float v = acc[mi][ni][r] + bias[nn];
          vbase[(size_t)((nn - 512) & 63) * 64] = f2bf(v);
        }
      }
    }
  #undef VMCNT_A
}

// ---------------- GEMM v4 (r14, bf16 A via gload_lds ring) — for g2 ---------
template<int OUT_MODE, int NB>            // OUT_MODE: 0=qkv split, 1=f32
__global__ __launch_bounds__(256, 2)
void gemm_v4(const ushort_t* __restrict__ A, int ldA,
             const ushort_t* __restrict__ Bt,
             const float* __restrict__ bias,
             void* __restrict__ Outp, int ldOut,
             ushort_t* __restrict__ Vt)
{
  __shared__ ushort_t Bl[64][256];          // 32 KB; 16B-chunk c at c^(r&7)
  __shared__ ushort_t Al[4][3][64][32];     // 48 KB; chunk c at c^((r>>1)&3)

  const int tid = threadIdx.x;
  const int lane = tid & 63;
  const int w  = tid >> 6;
  const int l15 = lane & 15, g = lane >> 4;

  const int nwg = NB * 64;
  const int inner = (int)blockIdx.x % nwg;
  const int chunkXCD = nwg >> 3;
  const int gidx = (inner & 7) * chunkXCD + (inner >> 3);
  const int n0 = (gidx % NB) * 64;
  const int mBase = (gidx / NB) * 256;
  const int mw = mBase + w * 64;            // this wave's 64 rows
  const bool vmode = (OUT_MODE == 0) && (n0 >= 512);

  #pragma unroll
  for (int i = 0; i < 8; ++i) {
    const int L = i * 256 + tid;
    const int r = L >> 5, c = L & 31;
    gload_lds16(&Bt[(size_t)(n0 + r) * 256 + (c ^ (r & 7)) * 8],
                &Bl[0][0] + (size_t)L * 8);
  }
  #pragma unroll
  for (int s = 0; s < 2; ++s)
    #pragma unroll
    for (int i = 0; i < 4; ++i) {
      const int L = i * 64 + lane;          // 256 chunks per slice
      const int r = L >> 2, c = L & 3;
      gload_lds16(&A[(size_t)(mw + r) * ldA + s*32 + (c ^ ((r >> 1) & 3)) * 8],
                  &Al[w][s][0][0] + (size_t)L * 8);
    }
  asm volatile("s_waitcnt vmcnt(8)" ::: "memory");
  BARRIER_RAW();

  f32x4 acc[4][4] = {};

  #pragma unroll
  for (int t = 0; t < 8; ++t) {             // K = 8 x 32, NO in-loop barriers
    if (t < 6) {
      #pragma unroll
      for (int i = 0; i < 4; ++i) {
        const int L = i * 64 + lane;
        const int r = L >> 2, c = L & 3;
        gload_lds16(&A[(size_t)(mw + r) * ldA + (t+2)*32
                       + (c ^ ((r >> 1) & 3)) * 8],
                    &Al[w][(t + 2) % 3][0][0] + (size_t)L * 8);
      }
    }
    if (t < 6)      asm volatile("s_waitcnt vmcnt(8)" ::: "memory");
    else if (t == 6) asm volatile("s_waitcnt vmcnt(4)" ::: "memory");
    else             asm volatile("s_waitcnt vmcnt(0)" ::: "memory");

    bf16x8 af[4], bfr[4];
    #pragma unroll
    for (int mi = 0; mi < 4; ++mi) {
      const int r = mi * 16 + l15;
      af[mi] = __builtin_bit_cast(bf16x8,
          *(const u16x8*)&Al[w][t % 3][r][(g ^ ((r >> 1) & 3)) * 8]);
    }
    #pragma unroll
    for (int ni = 0; ni < 4; ++ni) {
      const int r = ni * 16 + l15;
      bfr[ni] = __builtin_bit_cast(bf16x8,
          *(const u16x8*)&Bl[r][((t*4 + g) ^ (r & 7)) * 8]);
    }
    if (vmode) {
      #pragma unroll
      for (int mi = 0; mi < 4; ++mi)
        #pragma unroll
        for (int ni = 0; ni < 4; ++ni)
          acc[mi][ni] = __builtin_amdgcn_mfma_f32_16x16x32_bf16(
                            bfr[ni], af[mi], acc[mi][ni], 0, 0, 0);
    } else {
      #pragma unroll
      for (int mi = 0; mi < 4; ++mi)
        #pragma unroll
        for (int ni = 0; ni < 4; ++ni)
          acc[mi][ni] = __builtin_amdgcn_mfma_f32_16x16x32_bf16(
                            af[mi], bfr[ni], acc[mi][ni], 0, 0, 0);
    }
  }

  #pragma unroll
  for (int mi = 0; mi < 4; ++mi)
    #pragma unroll
    for (int ni = 0; ni < 4; ++ni) {
      if (!vmode) {
        const int col = n0 + ni * 16 + l15;
        const float bv = bias[col];
        #pragma unroll
        for (int r = 0; r < 4; ++r) {
          const int row = mw + mi * 16 + g * 4 + r;
          const float v = acc[mi][ni][r] + bv;
          if (OUT_MODE == 1)
            ((float*)Outp)[(size_t)row * ldOut + col] = v;
          else
            ((ushort_t*)Outp)[(size_t)row * 512 + col] = f2bf(v);
        }
      } else {
        const int hh = (n0 - 512) >> 6;
        const int m = mw + mi * 16 + l15;
        const int bb = m >> 10, ss = m & 1023;
        ushort_t* vbase =
            &Vt[(size_t)(((bb*4 + hh)*16 + (ss >> 6)) * 4096) + (ss & 63)];
        #pragma unroll
        for (int r = 0; r < 4; ++r) {
          const int nn = n0 + ni * 16 + g * 4 + r;     // 512..767
          const float v = acc[mi][ni][r] + bias[nn];
          vbase[(size_t)((nn - 512) & 63) * 64] = f2bf(v);
        }
      }
    }
}

// ---------------- kernel 2: causal flash attention (r17 verbatim) -----------
__global__ __launch_bounds__(256, 2)
void attn_kernel(ushort_t* __restrict__ qk, const ushort_t* __restrict__ Vt)
{
  __shared__ ushort_t K_lds[4][64][64];   // 32 KB ring
  __shared__ ushort_t V_lds[4][64][64];   // 32 KB ring (V^T tiles)

  const int lid = blockIdx.x;
  const int xc  = lid & 7;
  const int p   = (lid >> 3) & 7;
  const int bhi = lid >> 6;               // 0..7
  const int b   = 2 * xc + (bhi >> 2);
  const int h   = bhi & 3;
  const int bh  = b * 4 + h;
  const int qtA = p, qtB = 15 - p;

  const int tid = threadIdx.x;
  const int lane = tid & 63;
  const int w = tid >> 6;
  const int l15 = lane & 15, g = lane >> 4;

  const size_t rowbase = (size_t)b * 1024;
  const int qc = h * 64, kc = 256 + h * 64;
  const ushort_t* Vtt = Vt + (size_t)bh * 16 * 4096;

  bf16x8 qfA[2], qfB[2];
  {
    const size_t ra = rowbase + qtA*64 + w*16 + l15;
    const size_t rb = rowbase + qtB*64 + w*16 + l15;
    #pragma unroll
    for (int ks = 0; ks < 2; ++ks) {
      qfA[ks] = __builtin_bit_cast(bf16x8,
                  *(const u16x8*)&qk[ra*512 + qc + ks*32 + g*8]);
      qfB[ks] = __builtin_bit_cast(bf16x8,
                  *(const u16x8*)&qk[rb*512 + qc + ks*32 + g*8]);
    }
  }

  f32x4 oA[4] = {}, oB[4] = {};        // O^T frags: row d=da*16+g*4+r, col q=l15
  float lsA = 0.f, lsB = 0.f;
  const int qgA = qtA*64 + w*16 + l15;
  const int qgB = qtB*64 + w*16 + l15;

  auto stage = [&](int bi, int kt) {   // 4 gload/thread
    const int kv0 = kt * 64;
    const ushort_t* vtile = Vtt + kt * 4096;
    #pragma unroll
    for (int ri = 0; ri < 2; ++ri) {
      const int L = ri*256 + tid;      // 16B-chunk 0..511
      const int r = L >> 3;
      gload_lds16(&qk[(rowbase + kv0 + r)*512 + kc + ((L & 7) ^ (r & 7))*8],
                  &K_lds[bi][0][0] + (size_t)L*8);
      gload_lds16(&vtile[r*64 + ((L & 7) ^ ((r >> 1) & 7))*8],
                  &V_lds[bi][0][0] + (size_t)L*8);
    }
  };

  stage(0, 0);
  stage(1, 1);
  stage(2, 2);
  asm volatile("s_waitcnt vmcnt(8)" ::: "memory");   // tile 0 landed
  BARRIER_RAW();

  for (int kt = 0; kt <= qtB; ++kt) {
    const int cur = kt & 3;
    stage((kt + 3) & 3, (kt + 3 <= qtB) ? kt + 3 : qtB);

    bf16x8 kf[2][4];
    #pragma unroll
    for (int ks = 0; ks < 2; ++ks)
      #pragma unroll
      for (int ni = 0; ni < 4; ++ni) {
        const int row = ni*16 + l15;
        kf[ks][ni] = __builtin_bit_cast(bf16x8,
            *(const u16x8*)&K_lds[cur][row][(((ks*4 + g) ^ (row & 7))) * 8]);
      }
    bf16x4 vf[4][4];
    #pragma unroll
    for (int ni = 0; ni < 4; ++ni)
      #pragma unroll
      for (int da = 0; da < 4; ++da) {
        const int row = da*16 + l15;
        const int phys = (ni*2 + (g >> 1)) ^ ((row >> 1) & 7);
        vf[ni][da] = __builtin_bit_cast(bf16x4,
            *(const u16x4*)&V_lds[cur][row][phys*8 + (g & 1)*4]);
      }

    const int kv0 = kt * 64;
    const int g4 = g * 4;

    auto tile_step = [&](const bf16x8 (&qf)[2], f32x4 (&o)[4], float &ls,
                         int qg, bool diag) {
      f32x4 s[4] = {};
      #pragma unroll
      for (int ks = 0; ks < 2; ++ks)
        #pragma unroll
        for (int ni = 0; ni < 4; ++ni)
          s[ni] = __builtin_amdgcn_mfma_f32_16x16x32_bf16(kf[ks][ni], qf[ks],
                                                          s[ni], 0, 0, 0);
      bf16x4 pn[4];
      #pragma unroll
      for (int ni = 0; ni < 4; ++ni)
        #pragma unroll
        for (int r = 0; r < 4; ++r) {
          float e = exp2f(fmaf(s[ni][r], 0.18033688011112042f,
                               -14.426950408889634f));
          if (diag) e = (kv0 + ni*16 + g4 + r <= qg) ? e : 0.0f;
          ls += e;
          pn[ni][r] = (__bf16)e;
        }
      #pragma unroll
      for (int ni = 0; ni < 4; ++ni)
        #pragma unroll
        for (int da = 0; da < 4; ++da)
          o[da] = mfma16(vf[ni][da], pn[ni], o[da]);
    };

    tile_step(qfB, oB, lsB, qgB, kt == qtB);
    if (kt <= qtA) tile_step(qfA, oA, lsA, qgA, kt == qtA);

    asm volatile("s_waitcnt vmcnt(8)" ::: "memory");  // tile kt+1 landed
    BARRIER_RAW();
  }

  asm volatile("s_nop 7\n\ts_nop 7" :::);

  lsA += __shfl_xor(lsA, 16); lsA += __shfl_xor(lsA, 32);
  lsB += __shfl_xor(lsB, 16); lsB += __shfl_xor(lsB, 32);
  const float invA = 1.f / lsA;
  const float invB = 1.f / lsB;

  {
    const size_t rowA = rowbase + (size_t)qgA;
    const size_t rowB = rowbase + (size_t)qgB;
    #pragma unroll
    for (int da = 0; da < 4; ++da) {
      u16x4 ovA, ovB;
      #pragma unroll
      for (int r = 0; r < 4; ++r) {
        ovA[r] = f2bf(oA[da][r] * invA);
        ovB[r] = f2bf(oB[da][r] * invB);
      }
      *(u16x4*)&qk[rowA*512 + qc + da*16 + g*4] = ovA;
      *(u16x4*)&qk[rowB*512 + qc + da*16 + g*4] = ovB;
    }
  }
}

// ---------------- launcher --------------------------------------------------
extern "C" void kernel_launch(void* const* d_in, const int* in_sizes, int n_in,
                              void* d_out, int out_size, void* d_ws, size_t ws_size,
                              hipStream_t stream)
{
  const float* x     = (const float*)d_in[0];
  const float* W_qkv = (const float*)d_in[1];
  const float* b_qkv = (const float*)d_in[2];
  const float* W_out = (const float*)d_in[3];
  const float* b_out = (const float*)d_in[4];
  float* out = (float*)d_out;

  char* ws = (char*)d_ws;
  ushort_t* WqT = (ushort_t*)ws;                         // [768][256]
  ushort_t* WoT = (ushort_t*)(ws + 393216);              // [256][256]
  ushort_t* qk  = (ushort_t*)(ws + 524288);              // [16384][512]
  ushort_t* Vt  = (ushort_t*)(ws + 17301504);            // [64][16][64][64]

  // weights only (~1us)
  convert_wt<<<dim3(64), dim3(256), 0, stream>>>(W_qkv, W_out, WqT, WoT);
  // QKV projection, x fp32 consumed directly (fused convert): v5, 1536 blocks
  gemm_v5<1, 0, 12><<<dim3(1536), dim3(256), 0, stream>>>(
      x, 256, WqT, b_qkv, qk, 512, Vt);
  // causal flash attention (r17: XCD-affine, 4-deep rings)
  attn_kernel<<<dim3(512), dim3(256), 0, stream>>>(qk, Vt);
  // output projection: v4, 256 blocks
  gemm_v4<1, 4><<<dim3(256), dim3(256), 0, stream>>>(
      qk, 512, WoT, b_out, out, 256, nullptr);
}